// Round 19
// baseline (172.689 us; speedup 1.0000x reference)
//
#include <hip/hip_runtime.h>
#include <hip/hip_bf16.h>

#define NTOT 8192
#define FIN 128
#define FOUT 32
#define NH 4
#define NSEG 4
#define SEGJ (NTOT / NSEG)  // 2048

typedef __attribute__((ext_vector_type(4))) float f32x4;
typedef __attribute__((ext_vector_type(4))) int i32x4;
typedef __attribute__((ext_vector_type(4))) unsigned int u32x4;
typedef __attribute__((ext_vector_type(8))) __bf16 bf16x8;
typedef unsigned long long u64;
typedef unsigned int u32;

__device__ __forceinline__ unsigned short f2bf(float x) {
  __hip_bfloat16 h = __float2bfloat16(x);
  return *reinterpret_cast<unsigned short*>(&h);
}

__device__ __forceinline__ void dma16(const void* g, void* l) {
  __builtin_amdgcn_global_load_lds(
      (const __attribute__((address_space(1))) void*)g,
      (__attribute__((address_space(3))) void*)l, 16, 0, 0);
}

// ---------------- k0: bit-pack adj -> bits64T[j64][row] (8 MB). Streaming.
__global__ __launch_bounds__(256, 2) void k0_pack(
    const int* __restrict__ adj, u64* __restrict__ bits64T) {
  int row = blockIdx.x * 4 + (threadIdx.x >> 6);
  int l = threadIdx.x & 63;
  const int* ap = adj + (size_t)row * NTOT + l;
  u64* bp = bits64T + row;
#pragma unroll 4
  for (int j64 = 0; j64 < NTOT / 64; ++j64) {
    int v = ap[j64 * 64];
    u64 mske = __ballot(v != 0);
    if (l == 0) bp[(size_t)j64 * NTOT] = mske;
  }
}

// ---------------- k1: h = X @ W -> h [N][128] f32, plus B-fragment panels:
// panel[(p*256 + jt)*512 + l*8 + e] (bf16), p = hd*2+half,
//   value = h[node = jt*32 + (l>>4)*8 + e][p*16 + (l&15)]
__global__ __launch_bounds__(256, 2) void k1_project(
    const float* __restrict__ X, const float* __restrict__ W,
    float* __restrict__ h, unsigned short* __restrict__ panel) {
  __shared__ float Xs[32 * 128];
  __shared__ float Ws[32 * 128];
  __shared__ unsigned short Hs[128 * 40];  // [o][node_local], stride 40
  int t = threadIdx.x;
  int nb = blockIdx.x * 32;

  const f32x4* Xg = reinterpret_cast<const f32x4*>(X + (size_t)nb * FIN);
  f32x4* Xs4 = reinterpret_cast<f32x4*>(Xs);
#pragma unroll
  for (int r = 0; r < 4; ++r) Xs4[t + r * 256] = Xg[t + r * 256];

  int ng = t >> 5, oq = t & 31;
  int n0 = ng * 4, o0 = oq * 4;
  f32x4 acc[4];
#pragma unroll
  for (int nn = 0; nn < 4; ++nn) acc[nn] = (f32x4){0.f, 0.f, 0.f, 0.f};

  for (int kp = 0; kp < 4; ++kp) {
    __syncthreads();
#pragma unroll
    for (int r = 0; r < 4; ++r) {
      int q = t + r * 256;
      int flat = q * 4;
      int kk = flat >> 7;
      int c = flat & 127;
      int hdd = c >> 5;
      int oo = c & 31;
      *reinterpret_cast<f32x4*>(&Ws[kk * 128 + c]) =
          *reinterpret_cast<const f32x4*>(W + hdd * (FIN * FOUT) +
                                          (kp * 32 + kk) * FOUT + oo);
    }
    __syncthreads();
#pragma unroll 8
    for (int kk = 0; kk < 32; ++kk) {
      f32x4 wv = *reinterpret_cast<const f32x4*>(&Ws[kk * 128 + o0]);
#pragma unroll
      for (int nn = 0; nn < 4; ++nn)
        acc[nn] += Xs[(n0 + nn) * 128 + kp * 32 + kk] * wv;
    }
  }
#pragma unroll
  for (int nn = 0; nn < 4; ++nn) {
    *reinterpret_cast<f32x4*>(&h[(size_t)(nb + n0 + nn) * 128 + o0]) = acc[nn];
#pragma unroll
    for (int c = 0; c < 4; ++c)
      Hs[(o0 + c) * 40 + (n0 + nn)] = f2bf(acc[nn][c]);
  }
  __syncthreads();
  int jt = blockIdx.x;
#pragma unroll
  for (int it = 0; it < 2; ++it) {
    int item = t + it * 256;
    int p = item >> 6;
    int l = item & 63;
    int o = p * 16 + (l & 15);
    u32x4 v = *reinterpret_cast<const u32x4*>(&Hs[o * 40 + (l >> 4) * 8]);
    *reinterpret_cast<u32x4*>(panel + (size_t)(p * 256 + jt) * 512 + l * 8) = v;
  }
}

// ---------------- k2: two-plane tables. Sf/E1f/E2f f32 [hd][N];
// Tt packed per-macro 2KB blocks (u16): Tt[jm*1024 + hd*192 + arr*64 + jo],
// arr: 0=bf16(d), 1=bf16(exp d), 2=bf16(exp .2d)
__global__ __launch_bounds__(256, 2) void k2_scores(
    const float* __restrict__ h, const float* __restrict__ a_src,
    const float* __restrict__ a_dst, float* __restrict__ Sf,
    float* __restrict__ E1f, float* __restrict__ E2f,
    unsigned short* __restrict__ Tt) {
  int n = blockIdx.x * 256 + threadIdx.x;
  const f32x4* hv = reinterpret_cast<const f32x4*>(h + (size_t)n * 128);
  const f32x4* as4 = reinterpret_cast<const f32x4*>(a_src);
  const f32x4* ad4 = reinterpret_cast<const f32x4*>(a_dst);
  int jm = n >> 6, jo = n & 63;
#pragma unroll
  for (int hd = 0; hd < NH; ++hd) {
    f32x4 sa = {0.f, 0.f, 0.f, 0.f}, da = {0.f, 0.f, 0.f, 0.f};
#pragma unroll
    for (int q = 0; q < 8; ++q) {
      f32x4 x = hv[hd * 8 + q];
      sa += x * as4[hd * 8 + q];
      da += x * ad4[hd * 8 + q];
    }
    float s = (sa[0] + sa[1]) + (sa[2] + sa[3]);
    float d = (da[0] + da[1]) + (da[2] + da[3]);
    Sf[hd * NTOT + n] = s;
    E1f[hd * NTOT + n] = expf(s);
    E2f[hd * NTOT + n] = expf(0.2f * s);
    int ti = jm * 1024 + hd * 192 + jo;
    Tt[ti] = f2bf(d);
    Tt[ti + 64] = f2bf(expf(d));
    Tt[ti + 128] = f2bf(expf(0.2f * d));
  }
}

// ---------------- k3: bits-adj + two-plane masked-table softmax + PV.
// Wave = 16 rows x 2 heads; block = 4 waves = 64 rows x one head-pair.
// Panels (8KB/macro) + tables (2KB/macro) LDS-staged cooperatively,
// double-buffered, ONE barrier per macro. adj = 1 u64 bits load/macro/wave.
// All k3 traffic is L2-resident (bits 8MB, panels 2MB, tables 256KB).
__global__ __launch_bounds__(256)
__attribute__((amdgpu_waves_per_eu(2))) void k3_attn(
    const u64* __restrict__ bits64T, const float* __restrict__ Sf,
    const float* __restrict__ E1f, const float* __restrict__ E2f,
    const unsigned short* __restrict__ Tt,
    const unsigned short* __restrict__ panel, float* __restrict__ pacc,
    float* __restrict__ plsum) {
  const int N = NTOT;
  __shared__ char panelS[2][8192];
  __shared__ char tabS[2][2048];
  int tid = threadIdx.x;
  int w = tid >> 6, l = tid & 63;
  int bx = blockIdx.x;
  int itile = bx >> 3, hp = (bx >> 2) & 1, seg = bx & 3;
  int ibase = itile * 64;
  int m = l & 15, g = l >> 4, jc = g * 8;
  int rowbase = ibase + w * 16;
  int row = rowbase + m;
  int hd0 = hp * 2;
  int jm0 = seg * 32;

  float sv0 = Sf[hd0 * N + row];
  float sv1 = Sf[(hd0 + 1) * N + row];

  // stage sources: wave w stages global plane hp*4+w (local plane = w)
  const char* pgW = (const char*)panel +
                    ((size_t)(hp * 4 + w) * 256 + (size_t)seg * 64) * 1024;
  const char* tg = (const char*)Tt + (size_t)jm0 * 2048;
  const u64* bptr = bits64T + (size_t)jm0 * N + rowbase;

  f32x4 z4 = {0.f, 0.f, 0.f, 0.f};
  f32x4 aP0[2] = {z4, z4}, aP1[2] = {z4, z4}, aPs[2] = {z4, z4};
  f32x4 aN0[2] = {z4, z4}, aN1[2] = {z4, z4}, aNs[2] = {z4, z4};
  bf16x8 bones;
  {
    u32 pat = (m == 0) ? 0x3f803f80u : 0u;
    u32x4 tmp = {pat, pat, pat, pat};
    bones = *reinterpret_cast<bf16x8*>(&tmp);
  }

#define STAGE(t_)                                                       \
  {                                                                     \
    int tc_ = (t_) > 31 ? 31 : (t_);                                    \
    char* pb_ = panelS[(t_)&1];                                         \
    dma16(pgW + (size_t)tc_ * 2048 + l * 16, pb_ + w * 2048);           \
    dma16(pgW + (size_t)tc_ * 2048 + 1024 + l * 16,                     \
          pb_ + w * 2048 + 1024);                                       \
    if (w == 0) {                                                       \
      dma16(tg + (size_t)tc_ * 2048 + l * 16, tabS[(t_)&1]);            \
      dma16(tg + (size_t)tc_ * 2048 + 1024 + l * 16,                    \
            tabS[(t_)&1] + 1024);                                       \
    }                                                                   \
  }

  // halfword masks from adjacency byte (R6-proven path)
#define MKFB(MK, BY)                                                    \
  _Pragma("unroll") for (int p = 0; p < 4; ++p) {                       \
    u32 lo_ = (u32)(((int)((BY) << (31 - 2 * p))) >> 31);               \
    u32 hi_ = (u32)(((int)((BY) << (30 - 2 * p))) >> 31);               \
    MK[p] = __builtin_amdgcn_perm(hi_, lo_, 0x07060100u);               \
  }

#define MFM(AF, B, ACC) \
  ACC = __builtin_amdgcn_mfma_f32_16x16x32_bf16(AF, B, ACC, 0, 0, 0);

  // one AF (32 j) for one head: masked two-plane frags + 6 MFMA (R15-proven)
#define AFPLANE(HH, MK, Dv, F1v, F2v, B0, B1, SV)                         \
  {                                                                       \
    u32x4 aPw, aNw;                                                       \
    _Pragma("unroll") for (int p = 0; p < 4; ++p) {                       \
      float de = __uint_as_float((Dv)[p] << 16);                          \
      float dodd = __uint_as_float((Dv)[p] & 0xFFFF0000u);                \
      u32 n0 = (u32)(__float_as_int((SV) + de) >> 31);                    \
      u32 n1 = (u32)(__float_as_int((SV) + dodd) >> 31);                  \
      u32 mn = __builtin_amdgcn_perm(n1, n0, 0x05040100u);                \
      aPw[p] = (F1v)[p] & ((MK)[p] & ~mn);                                \
      aNw[p] = (F2v)[p] & ((MK)[p] & mn);                                 \
    }                                                                     \
    bf16x8 afP = *reinterpret_cast<bf16x8*>(&aPw);                        \
    bf16x8 afN = *reinterpret_cast<bf16x8*>(&aNw);                        \
    MFM(afP, B0, aP0[HH]) MFM(afP, B1, aP1[HH]) MFM(afP, bones, aPs[HH])  \
    MFM(afN, B0, aN0[HH]) MFM(afN, B1, aN1[HH]) MFM(afN, bones, aNs[HH])  \
  }

  STAGE(0)
  __syncthreads();  // stage-0 DMAs drained (compiler vmcnt(0) before barrier)

#pragma unroll 1
  for (int t = 0; t < 32; ++t) {
    int cur = t & 1;
    STAGE(t + 1)  // into buf cur^1; drained by this macro's end barrier
    u64 M = bptr[(size_t)t * N + m];
    u32 byA = ((u32)M >> jc) & 0xFFu;
    u32 byB = ((u32)(M >> 32) >> jc) & 0xFFu;
    u32x4 mkA, mkB;
    MKFB(mkA, byA)
    MKFB(mkB, byB)
    const char* pb = panelS[cur];
    const char* tb = tabS[cur];
#pragma unroll
    for (int hh = 0; hh < 2; ++hh) {
      int hdo = (hd0 + hh) * 384;
      float sv_ = hh ? sv1 : sv0;
      // tables: broadcast u32x4 reads (conflict-free: groups hit
      // disjoint bank quads)
      u32x4 DvA = *(const u32x4*)(tb + hdo + jc * 2);
      u32x4 DvB = *(const u32x4*)(tb + hdo + 64 + jc * 2);
      u32x4 F1A = *(const u32x4*)(tb + hdo + 128 + jc * 2);
      u32x4 F1B = *(const u32x4*)(tb + hdo + 192 + jc * 2);
      u32x4 F2A = *(const u32x4*)(tb + hdo + 256 + jc * 2);
      u32x4 F2B = *(const u32x4*)(tb + hdo + 320 + jc * 2);
      // panels: local plane = hh*2+half; jt half-tile at +jt*1024
      const char* p0 = pb + (hh * 2) * 2048 + l * 16;
      const char* p1 = pb + (hh * 2 + 1) * 2048 + l * 16;
      bf16x8 B0A = *(const bf16x8*)(p0);
      bf16x8 B0B = *(const bf16x8*)(p0 + 1024);
      bf16x8 B1A = *(const bf16x8*)(p1);
      bf16x8 B1B = *(const bf16x8*)(p1 + 1024);
      AFPLANE(hh, mkA, DvA, F1A, F2A, B0A, B1A, sv_)
      AFPLANE(hh, mkB, DvB, F1B, F2B, B0B, B1B, sv_)
    }
    __syncthreads();  // all reads of buf[cur] done; stage(t+1) drained
  }
#undef STAGE
#undef MKFB
#undef MFM
#undef AFPLANE

  // epilogue: D layout col=lane&15 (o), row=(lane>>4)*4+reg (i).
#pragma unroll
  for (int hh = 0; hh < 2; ++hh) {
    int hd = hd0 + hh;
    int rb = rowbase + g * 4;
#pragma unroll
    for (int r = 0; r < 4; ++r) {
      int rowr = rb + r;
      float e1 = E1f[hd * N + rowr], e2 = E2f[hd * N + rowr];
      if (m == 0)
        plsum[(seg * NH + hd) * N + rowr] = e1 * aPs[hh][r] + e2 * aNs[hh][r];
      pacc[((size_t)seg * N + rowr) * 128 + hd * 32 + m] =
          e1 * aP0[hh][r] + e2 * aN0[hh][r];
      pacc[((size_t)seg * N + rowr) * 128 + hd * 32 + 16 + m] =
          e1 * aP1[hh][r] + e2 * aN1[hh][r];
    }
  }
}

// ---------------- k4: combine segments + normalize
__global__ __launch_bounds__(256, 2) void k4_combine(
    const float* __restrict__ pacc, const float* __restrict__ plsum,
    float* __restrict__ out) {
  int idx = blockIdx.x * 256 + threadIdx.x;
  int i = idx >> 7;
  int c = idx & 127;
  int hd = c >> 5;
  float a = 0.f, ls = 0.f;
#pragma unroll
  for (int s = 0; s < NSEG; ++s) {
    a += pacc[((size_t)s * NTOT + i) * 128 + c];
    ls += plsum[(s * NH + hd) * NTOT + i];
  }
  out[idx] = (ls > 0.f) ? a / ls : 0.f;
}

extern "C" void kernel_launch(void* const* d_in, const int* in_sizes, int n_in,
                              void* d_out, int out_size, void* d_ws,
                              size_t ws_size, hipStream_t stream) {
  const float* X = (const float*)d_in[0];
  const int* adj = (const int*)d_in[1];
  const float* W = (const float*)d_in[2];
  const float* a_src = (const float*)d_in[3];
  const float* a_dst = (const float*)d_in[4];
  float* out = (float*)d_out;

  char* ws = (char*)d_ws;
  float* h = (float*)(ws + 0x0);                              // 4 MB
  unsigned short* panel = (unsigned short*)(ws + 0x400000);   // 2 MB
  float* Sf = (float*)(ws + 0x600000);                        // 128 KB
  float* E1f = (float*)(ws + 0x620000);                       // 128 KB
  float* E2f = (float*)(ws + 0x640000);                       // 128 KB
  unsigned short* Tt = (unsigned short*)(ws + 0x660000);      // 256 KB
  u64* bits64T = (u64*)(ws + 0x6A0000);                       // 8 MB
  float* pacc = (float*)(ws + 0xEA0000);                      // 16 MB
  float* plsum = (float*)(ws + 0x1EA0000);                    // 512 KB

  k0_pack<<<dim3(2048), dim3(256), 0, stream>>>(adj, bits64T);
  k1_project<<<dim3(256), dim3(256), 0, stream>>>(X, W, h, panel);
  k2_scores<<<dim3(32), dim3(256), 0, stream>>>(h, a_src, a_dst, Sf, E1f, E2f,
                                                Tt);
  k3_attn<<<dim3(128 * 2 * NSEG), dim3(256), 0, stream>>>(
      bits64T, Sf, E1f, E2f, Tt, panel, pacc, plsum);
  k4_combine<<<dim3(4096), dim3(256), 0, stream>>>(pacc, plsum, out);
}